// Round 1
// baseline (231.356 us; speedup 1.0000x reference)
//
#include <hip/hip_runtime.h>

typedef __attribute__((ext_vector_type(8))) short bf16x8;
typedef __attribute__((ext_vector_type(4))) float f32x4;
typedef __attribute__((ext_vector_type(2))) unsigned int u32x2;

#define B_N 8
#define S_N 2048
#define D_N 128
#define W_N 16
#define G_N 512
#define SP (S_N + W_N - 1) /* 2063 padded rows per batch */

// round-to-nearest-even fp32 -> bf16
__device__ __forceinline__ short f2bf(float f) {
  union { float f; unsigned u; } v; v.f = f;
  unsigned r = v.u + 0x7fffu + ((v.u >> 16) & 1u);
  return (short)(r >> 16);
}

__device__ __forceinline__ bf16x8 cvt8(const float* p) {
  f32x4 a = *(const f32x4*)p;
  f32x4 b = *(const f32x4*)(p + 4);
  bf16x8 v;
  v[0] = f2bf(a[0]); v[1] = f2bf(a[1]); v[2] = f2bf(a[2]); v[3] = f2bf(a[3]);
  v[4] = f2bf(b[0]); v[5] = f2bf(b[1]); v[6] = f2bf(b[2]); v[7] = f2bf(b[3]);
  return v;
}

__device__ __forceinline__ float sigm(float x) {
  return __builtin_amdgcn_rcpf(1.0f + __builtin_amdgcn_exp2f(-1.4426950408889634f * x));
}
__device__ __forceinline__ float tanh_(float x) {
  return 2.0f * __builtin_amdgcn_rcpf(1.0f + __builtin_amdgcn_exp2f(-2.8853900817779268f * x)) - 1.0f;
}

// ---------------------------------------------------------------------------
// Pass 0: fill the W-1 padding rows of xg with (b_ih + b_hh)   (x=0 there)
// ---------------------------------------------------------------------------
__global__ void pad_kernel(const float* __restrict__ b_ih, const float* __restrict__ b_hh,
                           float* __restrict__ xg) {
  int idx = blockIdx.x * 512 + threadIdx.x;   // 8*15*512 = 61440 total
  int g = idx & (G_N - 1);
  int p = (idx >> 9) % (W_N - 1);
  int b = idx / ((W_N - 1) * G_N);
  if (b < B_N)
    xg[((long)b * SP + p) * G_N + g] = b_ih[g] + b_hh[g];
}

// ---------------------------------------------------------------------------
// Pass 1: xg[b, t+15, g] = x[b,t] . w_ih[g] + b_ih[g] + b_hh[g]   (fp32 out)
// Block: 16 rows of x, 8 waves; wave wv computes gate tiles {wv, wv+8, wv+16, wv+24}.
// Swapped MFMA: D[g][row] = A(w_ih tile) * B(x^T).  C: col(lane&15)=row, row(4q+r)=g.
// ---------------------------------------------------------------------------
__global__ void __launch_bounds__(512, 4)
xg_kernel(const float* __restrict__ x, const float* __restrict__ w_ih,
          const float* __restrict__ b_ih, const float* __restrict__ b_hh,
          float* __restrict__ xg) {
  const int tid = threadIdx.x;
  const int lane = tid & 63;
  const int wv = tid >> 6;
  const int lm = lane & 15;
  const int q  = lane >> 4;
  const int n0 = blockIdx.x * 16;
  const int b  = n0 >> 11;
  const int t0 = n0 & (S_N - 1);

  // A fragments: w_ih[g = tg*16+lm][k = kt*32 + q*8 + j]
  bf16x8 wf[4][4];
#pragma unroll
  for (int i = 0; i < 4; ++i) {
    const int g = (wv + 8 * i) * 16 + lm;
#pragma unroll
    for (int kt = 0; kt < 4; ++kt)
      wf[i][kt] = cvt8(w_ih + g * D_N + kt * 32 + q * 8);
  }
  // B fragments: x^T[k][row=lm] -> x[n0+lm][k = kt*32 + q*8 + j]
  bf16x8 xf[4];
  const float* xr = x + (long)(n0 + lm) * D_N;
#pragma unroll
  for (int kt = 0; kt < 4; ++kt) xf[kt] = cvt8(xr + kt * 32 + q * 8);

  f32x4 acc[4] = {{0,0,0,0},{0,0,0,0},{0,0,0,0},{0,0,0,0}};
#pragma unroll
  for (int i = 0; i < 4; ++i)
#pragma unroll
    for (int kt = 0; kt < 4; ++kt)
      acc[i] = __builtin_amdgcn_mfma_f32_16x16x32_bf16(wf[i][kt], xf[kt], acc[i], 0, 0, 0);

  const long R = (long)b * SP + t0 + lm + (W_N - 1);
#pragma unroll
  for (int i = 0; i < 4; ++i) {
    const int g0 = (wv + 8 * i) * 16 + 4 * q;
    f32x4 bi = *(const f32x4*)(b_ih + g0);
    f32x4 bh = *(const f32x4*)(b_hh + g0);
    f32x4 v = acc[i];
    v.x += bi.x + bh.x; v.y += bi.y + bh.y; v.z += bi.z + bh.z; v.w += bi.w + bh.w;
    *(f32x4*)(xg + R * G_N + g0) = v;
  }
}

// ---------------------------------------------------------------------------
// Pass 2: 16-step LSTM recurrence. Block = 16 chains (consecutive s, same b),
// 8 waves; wave wv owns d-slice [16wv, 16wv+16) == gate tiles {wv,wv+8,wv+16,wv+24}
// so i,f,g,o for a (chain,d) are lane-local. w_hh fragments stay in VGPRs.
// h (bf16) round-trips through a double-buffered XOR-swizzled LDS tile.
// ---------------------------------------------------------------------------
__global__ void __launch_bounds__(512, 4)
rnn_kernel(const float* __restrict__ xg, const float* __restrict__ w_hh,
           float* __restrict__ out) {
  __shared__ char hbuf[2][16 * D_N * 2];   // [chain][k] bf16, swizzled, 2x4KB
  const int tid = threadIdx.x;
  const int lane = tid & 63;
  const int wv = tid >> 6;
  const int lm = lane & 15;
  const int q  = lane >> 4;
  const int n0 = blockIdx.x * 16;
  const int b  = n0 >> 11;
  const int s0 = n0 & (S_N - 1);

  // permanent A fragments: w_hh[g = tg*16+lm][k = kt*32 + q*8 + j]
  bf16x8 wf[4][4];
#pragma unroll
  for (int i = 0; i < 4; ++i) {
    const int g = (wv + 8 * i) * 16 + lm;
#pragma unroll
    for (int kt = 0; kt < 4; ++kt)
      wf[i][kt] = cvt8(w_hh + g * D_N + kt * 32 + q * 8);
  }

  // per-lane xg row: chain = lm -> padded row (s0+lm) + w
  const float* xgp = xg + ((long)b * SP + s0 + lm) * G_N;

  const int swz = (lm & 7) << 4;                              // bank swizzle
  const int wr_off = (lm * 256 + (16 * wv + 4 * q) * 2) ^ swz; // 8B store
  int rd_off[4];
#pragma unroll
  for (int kt = 0; kt < 4; ++kt)
    rd_off[kt] = (lm * 256 + kt * 64 + q * 16) ^ swz;          // 16B loads

  f32x4 c = {0.f, 0.f, 0.f, 0.f};
  float h[4] = {0.f, 0.f, 0.f, 0.f};

#pragma unroll
  for (int w = 0; w < W_N; ++w) {
    // gates init = xg row (b_ih + b_hh already folded in)
    f32x4 acc[4];
    const float* xr = xgp + (long)w * G_N;
#pragma unroll
    for (int i = 0; i < 4; ++i)
      acc[i] = *(const f32x4*)(xr + (wv + 8 * i) * 16 + 4 * q);

    if (w > 0) {
      __syncthreads();                       // prev step's h visible
      const char* bb = hbuf[(w - 1) & 1];
      bf16x8 hf[4];
#pragma unroll
      for (int kt = 0; kt < 4; ++kt)
        hf[kt] = *(const bf16x8*)(bb + rd_off[kt]);
#pragma unroll
      for (int i = 0; i < 4; ++i)
#pragma unroll
        for (int kt = 0; kt < 4; ++kt)
          acc[i] = __builtin_amdgcn_mfma_f32_16x16x32_bf16(wf[i][kt], hf[kt], acc[i], 0, 0, 0);
    }

    // acc[0]=i, acc[1]=f, acc[2]=g~, acc[3]=o  for d = 16wv + 4q + r, chain = lm
#pragma unroll
    for (int r = 0; r < 4; ++r) {
      float cn = sigm(acc[1][r]) * c[r] + sigm(acc[0][r]) * tanh_(acc[2][r]);
      c[r] = cn;
      h[r] = sigm(acc[3][r]) * tanh_(cn);
    }

    if (w < W_N - 1) {   // publish h (bf16) for next step
      unsigned lo = ((unsigned)(unsigned short)f2bf(h[0])) |
                    (((unsigned)(unsigned short)f2bf(h[1])) << 16);
      unsigned hi = ((unsigned)(unsigned short)f2bf(h[2])) |
                    (((unsigned)(unsigned short)f2bf(h[3])) << 16);
      u32x2 v = {lo, hi};
      *(u32x2*)(&hbuf[w & 1][wr_off]) = v;
    }
  }

  // final h (fp32, un-rounded) -> out[b][s][d]
  float* op = out + (long)(n0 + lm) * D_N + 16 * wv + 4 * q;
  f32x4 hv = {h[0], h[1], h[2], h[3]};
  *(f32x4*)op = hv;
}

// ---------------------------------------------------------------------------
extern "C" void kernel_launch(void* const* d_in, const int* in_sizes, int n_in,
                              void* d_out, int out_size, void* d_ws, size_t ws_size,
                              hipStream_t stream) {
  const float* x    = (const float*)d_in[0];
  const float* w_ih = (const float*)d_in[1];
  const float* w_hh = (const float*)d_in[2];
  const float* b_ih = (const float*)d_in[3];
  const float* b_hh = (const float*)d_in[4];
  float* out = (float*)d_out;
  float* xg  = (float*)d_ws;   // 8 * 2063 * 512 fp32 = 33.8 MB

  pad_kernel<<<120, 512, 0, stream>>>(b_ih, b_hh, xg);
  xg_kernel<<<(B_N * S_N) / 16, 512, 0, stream>>>(x, w_ih, b_ih, b_hh, xg);
  rnn_kernel<<<(B_N * S_N) / 16, 512, 0, stream>>>(xg, w_hh, out);
}